// Round 4
// baseline (103.204 us; speedup 1.0000x reference)
//
#include <hip/hip_runtime.h>
#include <cmath>

#define Bb 4
#define Ll 2048
#define Dd 1024
#define Hh 64

typedef float f32x4 __attribute__((ext_vector_type(4)));
typedef short s16x8 __attribute__((ext_vector_type(8)));

#if __has_builtin(__builtin_amdgcn_exp2f)
#define EXP2(x) __builtin_amdgcn_exp2f(x)
#else
#define EXP2(x) exp2f(x)
#endif
#define SCL 0.0450842200278f   /* (1/32) * log2(e) : scores kept in log2 domain */

__device__ __forceinline__ unsigned short f2bf(float f) {
    union { float f; unsigned int u; } v; v.f = f;
    unsigned int u = v.u;
    return (unsigned short)((u + 0x7FFFu + ((u >> 16) & 1u)) >> 16);  // RNE
}
__device__ __forceinline__ unsigned int pack2(float a, float b) {
    return (unsigned int)f2bf(a) | ((unsigned int)f2bf(b) << 16);
}

// ---------------- Kernel 0: Wq fp32 -> bf16 (once) ----------------
__global__ __launch_bounds__(256) void wq_cvt(const float* __restrict__ Wq,
                                              unsigned short* __restrict__ wqb) {
    const int i = (blockIdx.x * 256 + threadIdx.x) * 8;
    float4 a = *(const float4*)(Wq + i);
    float4 b = *(const float4*)(Wq + i + 4);
    uint4 p; p.x = pack2(a.x, a.y); p.y = pack2(a.z, a.w);
    p.z = pack2(b.x, b.y); p.w = pack2(b.z, b.w);
    *(uint4*)(wqb + i) = p;
}

// ---------------- Kernel 1: q = x @ Wq^T, bf16 MFMA, NO LDS / NO BARRIERS ----------------
// grid 256 x 128 thr (2 waves). Wave owns 16 rows x all 64 cols (4 C tiles).
// A-frag: in-register from 2 coalesced float4 x-loads + bf16 pack (A[m=lane&15][k=q_*8+j]).
// B-frag: straight from bf16 Wq in L2 (B[n=lane&15=h][k=q_*8+j]). Waves free-run.
__global__ __launch_bounds__(128) void proj_mfma(const float* __restrict__ x,
                                                 const unsigned short* __restrict__ wqb,
                                                 unsigned short* __restrict__ q,
                                                 unsigned short* __restrict__ qT) {
    const int t = threadIdx.x;
    const int lane = t & 63;
    const int wv = t >> 6;
    const int m15 = lane & 15, q_ = lane >> 4;
    const int row0 = blockIdx.x * 32 + wv * 16;
    const float* xr = x + (size_t)(row0 + m15) * Dd + q_ * 8;

    f32x4 acc[4];
#pragma unroll
    for (int i = 0; i < 4; ++i) acc[i] = (f32x4){0.f, 0.f, 0.f, 0.f};

#pragma unroll 4
    for (int ks = 0; ks < 32; ++ks) {
        float4 a = *(const float4*)(xr + ks * 32);
        float4 b = *(const float4*)(xr + ks * 32 + 4);
        union { s16x8 v; uint4 u; } A;
        A.u.x = pack2(a.x, a.y); A.u.y = pack2(a.z, a.w);
        A.u.z = pack2(b.x, b.y); A.u.w = pack2(b.z, b.w);
#pragma unroll
        for (int ct = 0; ct < 4; ++ct) {
            s16x8 B = *(const s16x8*)(wqb + (size_t)(ct * 16 + m15) * Dd + ks * 32 + q_ * 8);
            acc[ct] = __builtin_amdgcn_mfma_f32_16x16x32_bf16(A.v, B, acc[ct], 0, 0, 0);
        }
    }
    // C layout: row = q_*4+reg, col(h-local) = m15
    const int b = row0 >> 11;
    const int mloc = (row0 & 2047) + q_ * 4;
#pragma unroll
    for (int ct = 0; ct < 4; ++ct) {
        const int h = ct * 16 + m15;
        unsigned short u0 = f2bf(acc[ct][0]), u1 = f2bf(acc[ct][1]);
        unsigned short u2 = f2bf(acc[ct][2]), u3 = f2bf(acc[ct][3]);
        q[(size_t)(row0 + q_ * 4 + 0) * Hh + h] = u0;
        q[(size_t)(row0 + q_ * 4 + 1) * Hh + h] = u1;
        q[(size_t)(row0 + q_ * 4 + 2) * Hh + h] = u2;
        q[(size_t)(row0 + q_ * 4 + 3) * Hh + h] = u3;
        ushort4 pk; pk.x = u0; pk.y = u1; pk.z = u2; pk.w = u3;
        *(ushort4*)&qT[((size_t)(b * Hh + h)) * Ll + mloc] = pk;
    }
}

// ---------------- Kernel 2: split-KV MFMA flash (S transposed), COMPACT GRID ----------------
// grid (144, B): triangular index -> (qt, s), no dead blocks. Block 256 = 4 waves,
// wave w owns q-rows w*16..+15; lane(m15) owns one full q-row; scores in log2 domain.
__global__ __launch_bounds__(256, 3) void flash_mfma(const unsigned short* __restrict__ qg,
                                                     const unsigned short* __restrict__ qTg,
                                                     float* __restrict__ PO,
                                                     float* __restrict__ ML) {
    const int i = blockIdx.x;                       // 0..143
    const int b = blockIdx.y;
    int g = (int)((sqrtf(1.0f + 2.0f * (float)i) - 1.0f) * 0.5f);
    while (2 * g * (g + 1) > i) --g;                // fp-edge insurance
    while (2 * (g + 1) * (g + 2) <= i) ++g;
    const int r_ = i - 2 * g * (g + 1);             // [0, 4(g+1))
    const int qt = 4 * g + r_ / (g + 1);
    const int s  = r_ % (g + 1);

    __shared__ uint4 Qs4[512], Ks4[512], Vt4[512];            // 8 KB each
    __shared__ __align__(16) unsigned short Pb[4 * 16 * 72];  // P rows, stride 72 bf16
    const int t = threadIdx.x, lane = t & 63, w = t >> 6;
    const int m15 = lane & 15, q_ = lane >> 4;
    const unsigned short* qb  = qg  + (size_t)b * Ll * Hh;
    const unsigned short* qTb = qTg + (size_t)b * Hh * Ll;

#pragma unroll
    for (int j = 0; j < 2; ++j) {   // stage Q tile rows qt*64..+63
        int idx = t + j * 256;
        int r = idx >> 3, hc = idx & 7;
        Qs4[hc * 64 + (r ^ hc)] = *(const uint4*)(qb + (size_t)(qt * 64 + r) * Hh + hc * 8);
    }
    f32x4 Oacc[4];
#pragma unroll
    for (int k = 0; k < 4; ++k) Oacc[k] = (f32x4){0.f, 0.f, 0.f, 0.f};
    float mr = -INFINITY, lr = 0.f;
    const int n_it = min(4, qt - 4 * s + 1);
    const int c_base = s * 256;
    const int row = qt * 64 + w * 16 + m15;            // this lane's q-row
    unsigned short* Pr = Pb + (w * 16 + m15) * 72;     // wave-private P row

    for (int it = 0; it < n_it; ++it) {
        const int c0 = c_base + it * 64;
        __syncthreads();
#pragma unroll
        for (int j = 0; j < 2; ++j) {   // K tile
            int idx = t + j * 256;
            int c = idx >> 3, hc = idx & 7;
            Ks4[hc * 64 + (c ^ hc)] = *(const uint4*)(qb + (size_t)(c0 + c) * Hh + hc * 8);
        }
#pragma unroll
        for (int j = 0; j < 2; ++j) {   // V^T tile
            int idx = t + j * 256;
            int h = idx >> 3, cc = idx & 7;
            Vt4[cc * 64 + (h ^ cc)] = *(const uint4*)(qTb + (size_t)h * Ll + c0 + cc * 8);
        }
        __syncthreads();
        // S^T = K.Q^T : lane(m15,q_) -> q-row m15, kv-cols ct*16 + q_*4 + reg
        f32x4 sc[4];
#pragma unroll
        for (int ct = 0; ct < 4; ++ct) sc[ct] = (f32x4){0.f, 0.f, 0.f, 0.f};
#pragma unroll
        for (int ks = 0; ks < 2; ++ks) {
            int hc = ks * 4 + q_;
            s16x8 Bq = *(const s16x8*)&Qs4[hc * 64 + ((w * 16 + m15) ^ hc)];
#pragma unroll
            for (int ct = 0; ct < 4; ++ct) {
                s16x8 Ak = *(const s16x8*)&Ks4[hc * 64 + ((ct * 16 + m15) ^ hc)];
                sc[ct] = __builtin_amdgcn_mfma_f32_16x16x32_bf16(Ak, Bq, sc[ct], 0, 0, 0);
            }
        }
        const bool diag = (4 * s + it) == qt;
        float v[16];
#pragma unroll
        for (int ct = 0; ct < 4; ++ct)
#pragma unroll
            for (int r = 0; r < 4; ++r) {
                float sv = sc[ct][r] * SCL;            // log2-domain score
                if (diag && (c0 + ct * 16 + q_ * 4 + r > row)) sv = -INFINITY;
                v[ct * 4 + r] = sv;
            }
        float vmax = v[0];
#pragma unroll
        for (int k = 1; k < 16; ++k) vmax = fmaxf(vmax, v[k]);
        vmax = fmaxf(vmax, __shfl_xor(vmax, 16, 64));
        vmax = fmaxf(vmax, __shfl_xor(vmax, 32, 64));
        float mnew = fmaxf(mr, vmax);
        float alpha = EXP2(mr - mnew);                 // first iter: exp2(-inf)=0
        float p[16];
        float psum = 0.f;
#pragma unroll
        for (int k = 0; k < 16; ++k) { p[k] = EXP2(v[k] - mnew); psum += p[k]; }
        psum += __shfl_xor(psum, 16, 64);
        psum += __shfl_xor(psum, 32, 64);
        lr = lr * alpha + psum;
        mr = mnew;
#pragma unroll
        for (int ht = 0; ht < 4; ++ht) Oacc[ht] *= alpha;
#pragma unroll
        for (int ct = 0; ct < 4; ++ct) {               // P row (same-wave RAW, no barrier)
            uint2 pr; pr.x = pack2(p[ct * 4 + 0], p[ct * 4 + 1]);
            pr.y = pack2(p[ct * 4 + 2], p[ct * 4 + 3]);
            *(uint2*)(Pr + ct * 16 + q_ * 4) = pr;
        }
        // O^T += V^T . P
#pragma unroll
        for (int kc = 0; kc < 2; ++kc) {
            int cc = kc * 4 + q_;
            s16x8 Bp = *(const s16x8*)(Pr + kc * 32 + q_ * 8);
#pragma unroll
            for (int ht = 0; ht < 4; ++ht) {
                s16x8 Av = *(const s16x8*)&Vt4[cc * 64 + ((ht * 16 + m15) ^ cc)];
                Oacc[ht] = __builtin_amdgcn_mfma_f32_16x16x32_bf16(Av, Bp, Oacc[ht], 0, 0, 0);
            }
        }
    }
    // epilogue: D col = q-row (m15), h-contiguous float4
    const size_t base = ((size_t)((b * 32 + qt) * 8 + s)) * 4096;
#pragma unroll
    for (int ht = 0; ht < 4; ++ht)
        *(f32x4*)&PO[base + (size_t)(w * 16 + m15) * 64 + ht * 16 + q_ * 4] = Oacc[ht];
    if (q_ == 0) {
        float* mlp = ML + ((size_t)((b * 32 + qt) * 8 + s)) * 128;
        mlp[(w * 16 + m15) * 2 + 0] = mr;              // log2-domain max
        mlp[(w * 16 + m15) * 2 + 1] = lr;
    }
}

// ---------------- Kernel 3: combine slices (log2 domain) ----------------
__global__ __launch_bounds__(256) void combine_k(const float* __restrict__ PO,
                                                 const float* __restrict__ ML,
                                                 float* __restrict__ out) {
    const int bq = blockIdx.x;
    const int qt = bq & 31;
    const int b = bq >> 5;
    const int ns = (qt >> 2) + 1;
    const int t = threadIdx.x;
    const int r = blockIdx.y * 32 + (t >> 3);
    const int c8 = (t & 7) * 8;
    const float* mlp = ML + (size_t)bq * 8 * 128;
    const float* pob = PO + (size_t)bq * 8 * 4096;
    float M = -INFINITY;
    for (int si = 0; si < ns; ++si) M = fmaxf(M, mlp[si * 128 + r * 2]);
    float L = 0.f;
    f32x4 a0 = {0.f, 0.f, 0.f, 0.f}, a1 = a0;
    for (int si = 0; si < ns; ++si) {
        float ms = mlp[si * 128 + r * 2], ls = mlp[si * 128 + r * 2 + 1];
        float wgt = EXP2(ms - M);
        L += ls * wgt;
        const f32x4* sp = (const f32x4*)(pob + (size_t)si * 4096 + r * 64 + c8);
        a0 += wgt * sp[0];
        a1 += wgt * sp[1];
    }
    float inv = 1.0f / L;
    f32x4* op = (f32x4*)(out + (size_t)(b * Ll + qt * 64 + r) * 64 + c8);
    op[0] = a0 * inv;
    op[1] = a1 * inv;
}

extern "C" void kernel_launch(void* const* d_in, const int* in_sizes, int n_in,
                              void* d_out, int out_size, void* d_ws, size_t ws_size,
                              hipStream_t stream) {
    const float* x  = (const float*)d_in[0];   // [4,2048,1024]
    const float* Wq = (const float*)d_in[1];   // [64,1024]
    float* out = (float*)d_out;                // [4,2048,64] fp32
    char* ws = (char*)d_ws;
    unsigned short* q   = (unsigned short*)ws;                 // 1 MB  bf16 [B*L][64]
    unsigned short* qT  = (unsigned short*)(ws + (1 << 20));   // 1 MB  bf16 [B][64][L]
    float* PO = (float*)(ws + (2 << 20));                      // 16 MB partials
    float* ML = (float*)(ws + (18 << 20));                     // 512 KB (m,l)
    unsigned short* wqb = (unsigned short*)(ws + (19 << 20));  // 128 KB Wq bf16

    wq_cvt<<<32, 256, 0, stream>>>(Wq, wqb);
    proj_mfma<<<256, 128, 0, stream>>>(x, wqb, q, qT);
    flash_mfma<<<dim3(144, Bb), 256, 0, stream>>>(q, qT, PO, ML);
    combine_k<<<dim3(128, 2), 256, 0, stream>>>(PO, ML, out);
}